// Round 17
// baseline (66.096 us; speedup 1.0000x reference)
//
#include <hip/hip_runtime.h>
#include <hip/hip_bf16.h>

#define N_ROWS 16384
#define DIM 128

constexpr float INV_T = 1.0f / 0.07f;                 // 14.2857...
constexpr float LOG2E = 1.4426950408889634f;
constexpr float C1    = INV_T * LOG2E;                // 20.6099  (exp2 scale)
constexpr float SOP   = 4.5398160f;                   // sqrt(C1), split per operand
constexpr float LN2   = 0.69314718055994530942f;

typedef int   v4i    __attribute__((ext_vector_type(4)));
typedef int   v8i    __attribute__((ext_vector_type(8)));
typedef float f32x16 __attribute__((ext_vector_type(16)));

// p8 PRE-TILED as the B-operand of mfma_scale_f32_32x32x64_f8f6f4 (proven R14):
// one 32-col tile = 4KB contiguous: [c2][h2][b2][col32][16B]
#define TILE_BYTES 4096
#define BM 256                        /* rows per block (4 waves x 64)    */
#define WROWS 64
#define COLSPLIT 16
#define COLS_PER (N_ROWS / COLSPLIT)  /* 1024 */
#define NJT (COLS_PER / 32)           /* 32 tiles */

// ---------------------------------------------------------------------------
// Kernel 1: normalize; both operands scaled by sqrt(C1); fp8 e4m3 outputs
// (A row-major, P tiled); exact fp32 diagonal logit; zeroes sacc. (proven R14)
// ---------------------------------------------------------------------------
__global__ __launch_bounds__(256) void norm_kernel(
    const float* __restrict__ A, const float* __restrict__ P,
    ushort* __restrict__ a8u, ushort* __restrict__ p8u,
    float* __restrict__ diag, float* __restrict__ sacc)
{
    if (threadIdx.x < 4) sacc[blockIdx.x * 4 + threadIdx.x] = 0.f;
    int row  = blockIdx.x * 4 + (threadIdx.x >> 6);
    int lane = threadIdx.x & 63;
    float2 av = *(const float2*)(A + (size_t)row * DIM + lane * 2);
    float2 pv = *(const float2*)(P + (size_t)row * DIM + lane * 2);
    float ssa = av.x * av.x + av.y * av.y;
    float ssp = pv.x * pv.x + pv.y * pv.y;
    float dp  = av.x * pv.x + av.y * pv.y;
    #pragma unroll
    for (int m = 1; m < 64; m <<= 1) {
        ssa += __shfl_xor(ssa, m);
        ssp += __shfl_xor(ssp, m);
        dp  += __shfl_xor(dp,  m);
    }
    float ra = 1.0f / fmaxf(sqrtf(ssa), 1e-12f);
    float rp = 1.0f / fmaxf(sqrtf(ssp), 1e-12f);
    if (lane == 0) diag[row] = dp * ra * rp * INV_T;
    float sa = ra * SOP, sp = rp * SOP;
    int apk = __builtin_amdgcn_cvt_pk_fp8_f32(av.x * sa, av.y * sa, 0, false);
    int ppk = __builtin_amdgcn_cvt_pk_fp8_f32(pv.x * sp, pv.y * sp, 0, false);
    a8u[(size_t)row * 64 + lane] = (ushort)apk;
    size_t off = (size_t)(row >> 5) * 2048 + (lane >> 5) * 1024
               + ((lane >> 4) & 1) * 512 + ((lane >> 3) & 1) * 256
               + (row & 31) * 8 + (lane & 7);
    p8u[off] = (ushort)ppk;
}

// ---------------------------------------------------------------------------
// Kernel 2: per-row sum of exp2(C1*cos - C1) via MX-fp8 32x32x64 MFMA.
// R16 structure (no LDS, no barriers, register-prefetch from L2, named
// even/odd load sets) + ONE edit: DETERMINISTIC WAVE STAGGER — wave w
// starts its modular tile walk at (8w + 2*colseg) & 31, so SIMD-mates sit
// at different pipeline phases (one in MFMA window while another is in its
// exp window; m114: the pipes co-execute across waves). Tile-sum order is
// irrelevant to the result.
// REG-CAP DISCIPLINE: (256,2) ONLY — tighter caps spill (R2/R4/R6).
// ---------------------------------------------------------------------------
__global__ __launch_bounds__(256, 2) void lse_kernel(
    const ushort* __restrict__ a8u, const ushort* __restrict__ p8u,
    float* __restrict__ s_accum)
{
    int colseg = blockIdx.x & (COLSPLIT - 1);   // bid%8 -> XCD-pinned segment
    int rowblk = blockIdx.x / COLSPLIT;
    int wave = threadIdx.x >> 6;
    int lane = threadIdx.x & 63;
    int c31  = lane & 31, hi = lane >> 5;
    int row0 = rowblk * BM + wave * WROWS;

    // A fragments: 2 row-tiles x 2 K-chunks, 32B/lane (v8i), row-major a8
    const char* a8 = (const char*)a8u;
    v8i afA0 = *(const v8i*)(a8 + (size_t)(row0 + c31) * 128 +       hi * 32);
    v8i afA1 = *(const v8i*)(a8 + (size_t)(row0 + c31) * 128 + 64  + hi * 32);
    v8i afB0 = *(const v8i*)(a8 + (size_t)(row0 + 32 + c31) * 128 +      hi * 32);
    v8i afB1 = *(const v8i*)(a8 + (size_t)(row0 + 32 + c31) * 128 + 64 + hi * 32);

    f32x16 cinit;
    #pragma unroll
    for (int r = 0; r < 16; ++r) cinit[r] = -C1;

    float s0[16], s1[16];
    #pragma unroll
    for (int r = 0; r < 16; ++r) { s0[r] = 0.f; s1[r] = 0.f; }

    // per-lane base into the tiled B segment (layout proven R14)
    const char* base = (const char*)p8u
                     + (size_t)colseg * NJT * TILE_BYTES + hi * 1024 + c31 * 16;

    // stagger: wave-dependent start of the modular tile walk
    int start = (wave * 8 + colseg * 2) & (NJT - 1);

    v4i eX0, eY0, eX1, eY1;    // even-step load set
    v4i oX0, oY0, oX1, oY1;    // odd-step load set

#define TOFF(k) ((size_t)(((start + (k)) & (NJT - 1))) * TILE_BYTES)
#define LOADSET_E(k) { const char* tb = base + TOFF(k);                       \
        eX0 = *(const v4i*)(tb);        eY0 = *(const v4i*)(tb + 512);        \
        eX1 = *(const v4i*)(tb + 2048); eY1 = *(const v4i*)(tb + 2560); }
#define LOADSET_O(k) { const char* tb = base + TOFF(k);                       \
        oX0 = *(const v4i*)(tb);        oY0 = *(const v4i*)(tb + 512);        \
        oX1 = *(const v4i*)(tb + 2048); oY1 = *(const v4i*)(tb + 2560); }

#define COMPUTE(X0, Y0, X1, Y1) {                                             \
        v8i b0 = __builtin_shufflevector(X0, Y0, 0, 1, 2, 3, 4, 5, 6, 7);     \
        v8i b1 = __builtin_shufflevector(X1, Y1, 0, 1, 2, 3, 4, 5, 6, 7);     \
        __builtin_amdgcn_s_setprio(1);                                        \
        f32x16 acc0 = __builtin_amdgcn_mfma_scale_f32_32x32x64_f8f6f4(        \
            afA0, b0, cinit, 0, 0, 0, 0x7f7f7f7f, 0, 0x7f7f7f7f);             \
        f32x16 acc1 = __builtin_amdgcn_mfma_scale_f32_32x32x64_f8f6f4(        \
            afB0, b0, cinit, 0, 0, 0, 0x7f7f7f7f, 0, 0x7f7f7f7f);             \
        acc0 = __builtin_amdgcn_mfma_scale_f32_32x32x64_f8f6f4(               \
            afA1, b1, acc0, 0, 0, 0, 0x7f7f7f7f, 0, 0x7f7f7f7f);              \
        acc1 = __builtin_amdgcn_mfma_scale_f32_32x32x64_f8f6f4(               \
            afB1, b1, acc1, 0, 0, 0, 0x7f7f7f7f, 0, 0x7f7f7f7f);              \
        __builtin_amdgcn_s_setprio(0);                                        \
        _Pragma("unroll")                                                     \
        for (int r = 0; r < 16; ++r) {                                        \
            s0[r] += __builtin_amdgcn_exp2f(acc0[r]);                         \
            s1[r] += __builtin_amdgcn_exp2f(acc1[r]);                         \
        } }

    // prologue: steps 0 (even set) and 1 (odd set) in flight
    LOADSET_E(0);
    LOADSET_O(1);

    for (int m = 0; m < 15; ++m) {
        v4i x0 = eX0, y0 = eY0, x1 = eX1, y1 = eY1;
        LOADSET_E(2 * m + 2);
        COMPUTE(x0, y0, x1, y1);                       // step 2m
        v4i u0 = oX0, v0 = oY0, u1 = oX1, v1 = oY1;
        LOADSET_O(2 * m + 3);
        COMPUTE(u0, v0, u1, v1);                       // step 2m+1
    }
    COMPUTE(eX0, eY0, eX1, eY1);                       // step 30
    COMPUTE(oX0, oY0, oX1, oY1);                       // step 31

#undef TOFF
#undef LOADSET_E
#undef LOADSET_O
#undef COMPUTE

    // reduce each row's 32 column-lanes (within each 32-lane half), one atomic
    #pragma unroll
    for (int t = 0; t < 2; ++t)
        #pragma unroll
        for (int r = 0; r < 16; ++r) {
            float v = (t ? s1[r] : s0[r]);
            v += __shfl_xor(v, 1);
            v += __shfl_xor(v, 2);
            v += __shfl_xor(v, 4);
            v += __shfl_xor(v, 8);
            v += __shfl_xor(v, 16);
            if (c31 == 0)
                atomicAdd(&s_accum[row0 + t * 32 + (r & 3) + 8 * (r >> 2) + 4 * hi], v);
        }
}

// ---------------------------------------------------------------------------
// Kernel 3: loss = mean( ln(s_i) + 1/T - diag_i )
// ---------------------------------------------------------------------------
__global__ __launch_bounds__(1024) void finalize_kernel(
    const float* __restrict__ s_acc, const float* __restrict__ diag,
    float* __restrict__ out)
{
    float acc = 0.f;
    int t = threadIdx.x;
    #pragma unroll
    for (int i = 0; i < 4; ++i) {
        int idx = (i * 1024 + t) * 4;
        float4 sv = *(const float4*)(s_acc + idx);
        float4 dv = *(const float4*)(diag + idx);
        acc += __builtin_amdgcn_logf(sv.x) * LN2 + INV_T - dv.x;
        acc += __builtin_amdgcn_logf(sv.y) * LN2 + INV_T - dv.y;
        acc += __builtin_amdgcn_logf(sv.z) * LN2 + INV_T - dv.z;
        acc += __builtin_amdgcn_logf(sv.w) * LN2 + INV_T - dv.w;
    }
    #pragma unroll
    for (int m = 1; m < 64; m <<= 1) acc += __shfl_xor(acc, m);
    __shared__ float wsum[16];
    if ((t & 63) == 0) wsum[t >> 6] = acc;
    __syncthreads();
    if (t == 0) {
        float r = 0.f;
        #pragma unroll
        for (int i = 0; i < 16; ++i) r += wsum[i];
        out[0] = r / (float)N_ROWS;
    }
}

// ---------------------------------------------------------------------------
extern "C" void kernel_launch(void* const* d_in, const int* in_sizes, int n_in,
                              void* d_out, int out_size, void* d_ws, size_t ws_size,
                              hipStream_t stream)
{
    const float* A = (const float*)d_in[0];
    const float* P = (const float*)d_in[1];
    float* out = (float*)d_out;

    char* ws = (char*)d_ws;
    ushort* a8u  = (ushort*)ws;                                   // 2 MB fp8
    ushort* p8u  = (ushort*)(ws + (size_t)2 * 1024 * 1024);       // 2 MB fp8 tiled
    float*  diag = (float*)(ws + (size_t)4 * 1024 * 1024);        // 64 KB
    float*  sacc = (float*)(ws + (size_t)4 * 1024 * 1024 + 65536);

    norm_kernel<<<N_ROWS / 4, 256, 0, stream>>>(A, P, a8u, p8u, diag, sacc);
    lse_kernel<<<(N_ROWS / BM) * COLSPLIT, 256, 0, stream>>>(a8u, p8u, sacc);
    finalize_kernel<<<1, 1024, 0, stream>>>(sacc, diag, out);
}